// Round 2
// baseline (335.708 us; speedup 1.0000x reference)
//
#include <hip/hip_runtime.h>
#include <stdint.h>

// Problem constants (fixed by reference)
#define BATCH 16
#define CH    512
#define HW    2304           // 48*48
#define BM    64
#define BN    128
#define BK    32
#define NT    (HW / BK)      // 72 K-tiles

// float -> order-preserving uint32 (monotone: a<b  <=>  key(a)<key(b))
__device__ __forceinline__ uint32_t f32_sortable(float f) {
    uint32_t u = __float_as_uint(f);
    return (u & 0x80000000u) ? ~u : (u | 0x80000000u);
}

// K1: energy = Q.K^T per batch (NT GEMM, fp32 vector FMA), fused row-argmax
// epilogue via packed atomicMax. best[b*CH+c] = (sortable(val)<<32) | ~d
// Grid 4x8x16 = 512 blocks -> 2 blocks/CU -> 2 waves/SIMD (R1 was 1: 53% VALUBusy)
__global__ __launch_bounds__(256, 2)
void energy_argmax_kernel(const float* __restrict__ q,    // rgb   [B][C][HW]
                          const float* __restrict__ kmat, // depth [B][C][HW]
                          unsigned long long* __restrict__ best) // [B][C]
{
    const int b  = blockIdx.z;
    const int c0 = blockIdx.y * BM;   // 8 tiles of 64 rows
    const int d0 = blockIdx.x * BN;   // 4 tiles of 128 cols
    const int tid = threadIdx.x;

    __shared__ float As[BK][BM + 4];   // 32 x 68  (8.7 KB)
    __shared__ float Bs[BK][BN + 4];   // 32 x 132 (16.9 KB)

    const float* qb = q    + (size_t)b * CH * HW;
    const float* kb = kmat + (size_t)b * CH * HW;

    // load mapping: L -> row = L>>3, k-offset = (L&7)*4   (BK=32 -> 8 float4 per row)
    float4 ra[2], rb[4];
    #pragma unroll
    for (int i = 0; i < 2; ++i) {
        int L = tid + i * 256, row = L >> 3, cv = (L & 7) * 4;
        ra[i] = *(const float4*)(qb + (size_t)(c0 + row) * HW + cv);
    }
    #pragma unroll
    for (int i = 0; i < 4; ++i) {
        int L = tid + i * 256, row = L >> 3, cv = (L & 7) * 4;
        rb[i] = *(const float4*)(kb + (size_t)(d0 + row) * HW + cv);
    }

    float acc[4][8];
    #pragma unroll
    for (int i = 0; i < 4; ++i)
        #pragma unroll
        for (int j = 0; j < 8; ++j) acc[i][j] = 0.0f;

    const int tx = tid & 15;   // n dim: 16 threads x 8 cols = 128
    const int ty = tid >> 4;   // m dim: 16 threads x 4 rows = 64
    const int m0 = ty * 4, n0 = tx * 8;

    for (int kt = 0; kt < NT; ++kt) {
        __syncthreads();   // previous compute done -> LDS reusable
        #pragma unroll
        for (int i = 0; i < 2; ++i) {
            int L = tid + i * 256, row = L >> 3, cv = (L & 7) * 4;
            As[cv + 0][row] = ra[i].x; As[cv + 1][row] = ra[i].y;
            As[cv + 2][row] = ra[i].z; As[cv + 3][row] = ra[i].w;
        }
        #pragma unroll
        for (int i = 0; i < 4; ++i) {
            int L = tid + i * 256, row = L >> 3, cv = (L & 7) * 4;
            Bs[cv + 0][row] = rb[i].x; Bs[cv + 1][row] = rb[i].y;
            Bs[cv + 2][row] = rb[i].z; Bs[cv + 3][row] = rb[i].w;
        }
        __syncthreads();
        if (kt + 1 < NT) {   // prefetch next tile into regs; hides under FMAs
            int k0 = (kt + 1) * BK;
            #pragma unroll
            for (int i = 0; i < 2; ++i) {
                int L = tid + i * 256, row = L >> 3, cv = (L & 7) * 4;
                ra[i] = *(const float4*)(qb + (size_t)(c0 + row) * HW + k0 + cv);
            }
            #pragma unroll
            for (int i = 0; i < 4; ++i) {
                int L = tid + i * 256, row = L >> 3, cv = (L & 7) * 4;
                rb[i] = *(const float4*)(kb + (size_t)(d0 + row) * HW + k0 + cv);
            }
        }
        #pragma unroll
        for (int kk = 0; kk < BK; ++kk) {
            float a[4], bb[8];
            *(float4*)&a[0]  = *(const float4*)&As[kk][m0];       // broadcast (16 lanes/addr)
            *(float4*)&bb[0] = *(const float4*)&Bs[kk][n0];
            *(float4*)&bb[4] = *(const float4*)&Bs[kk][n0 + 4];
            #pragma unroll
            for (int i = 0; i < 4; ++i)
                #pragma unroll
                for (int j = 0; j < 8; ++j)
                    acc[i][j] = fmaf(a[i], bb[j], acc[i][j]);
        }
    }

    // Epilogue: per-row argmax over this 128-col tile, then one atomic per row
    #pragma unroll
    for (int i = 0; i < 4; ++i) {
        int row = m0 + i;
        float vmax = acc[i][0];
        int   dmax = d0 + n0;
        #pragma unroll
        for (int j = 1; j < 8; ++j) {
            float v = acc[i][j];
            if (v > vmax) { vmax = v; dmax = d0 + n0 + j; }
        }
        unsigned long long p =
            ((unsigned long long)f32_sortable(vmax) << 32) |
            (uint32_t)(~(uint32_t)dmax);   // ties -> smallest d (numpy argmax)
        // reduce across the 16 tx lanes of this ty group (butterfly; stays in group)
        #pragma unroll
        for (int off = 1; off < 16; off <<= 1) {
            unsigned long long o = __shfl_xor(p, off, 64);
            if (o > p) p = o;
        }
        if (tx == 0)
            atomicMax(&best[(size_t)b * CH + c0 + row], p);
    }
}

// K2: out[b][c][:] = rgb[b][c][:] + depth[b][argmax][:]
__global__ __launch_bounds__(256)
void gather_add_kernel(const float* __restrict__ rgb,
                       const float* __restrict__ depth,
                       const unsigned long long* __restrict__ best,
                       float* __restrict__ out)
{
    const int row = blockIdx.x;          // b*CH + c
    const int b   = row >> 9;            // /512
    const uint32_t idx = ~(uint32_t)(best[row] & 0xFFFFFFFFull);
    const float4* src = (const float4*)(rgb   + (size_t)row * HW);
    const float4* dep = (const float4*)(depth + ((size_t)b * CH + idx) * HW);
    float4*       dst = (float4*)(out + (size_t)row * HW);
    for (int j = threadIdx.x; j < HW / 4; j += 256) {
        float4 a = src[j], d = dep[j];
        float4 r; r.x = a.x + d.x; r.y = a.y + d.y; r.z = a.z + d.z; r.w = a.w + d.w;
        dst[j] = r;
    }
}

extern "C" void kernel_launch(void* const* d_in, const int* in_sizes, int n_in,
                              void* d_out, int out_size, void* d_ws, size_t ws_size,
                              hipStream_t stream)
{
    const float* rgb   = (const float*)d_in[0];
    const float* depth = (const float*)d_in[1];
    float* out = (float*)d_out;
    unsigned long long* best = (unsigned long long*)d_ws;  // 16*512*8 = 64 KB

    hipMemsetAsync(best, 0, (size_t)BATCH * CH * sizeof(unsigned long long), stream);

    dim3 g1(CH / BN, CH / BM, BATCH);   // 4 x 8 x 16 = 512 blocks
    energy_argmax_kernel<<<g1, 256, 0, stream>>>(rgb, depth, best);

    gather_add_kernel<<<BATCH * CH, 256, 0, stream>>>(rgb, depth, best, out);
}

// Round 4
// 268.470 us; speedup vs baseline: 1.2504x; 1.2504x over previous
//
#include <hip/hip_runtime.h>
#include <stdint.h>

// Problem constants (fixed by reference)
#define BATCH 16
#define CH    512
#define HW    2304           // 48*48
#define BM    128
#define BN    64
#define BK    32
#define NKT   (HW / BK)      // 72 K-steps

typedef _Float16 half8  __attribute__((ext_vector_type(8)));
typedef float    f32x16 __attribute__((ext_vector_type(16)));

// LDS byte layout per buffer: A-hi | A-lo | B-hi | B-lo
#define AH_OFF 0
#define AL_OFF 8192          // 128 rows * 64B
#define BH_OFF 16384
#define BL_OFF 20480         // 64 rows * 64B
#define BUF_SZ 24576         // 24 KB ; x2 buffers = 48 KB

// float -> order-preserving uint32
__device__ __forceinline__ uint32_t f32_sortable(float f) {
    uint32_t u = __float_as_uint(f);
    return (u & 0x80000000u) ? ~u : (u | 0x80000000u);
}

// Swizzled byte offset in a [rows][32 f16] tile (row pitch 64B).
// Slot (16B unit, bits 4-5) is XORed with (r&3): stays inside the row ->
// bijective (R3's (r&7)<<4 overflowed bit6 into the next row: swz(7,0)==swz(8,48)).
// Wave b128 reads (rows=lane&31, fixed slot): all 4 slots x even/odd rows
// -> exactly 8 words/bank = conflict-free optimum.
__device__ __forceinline__ int swz(int r, int cb) {
    return r * 64 + (cb ^ ((r & 3) << 4));
}

__device__ __forceinline__ void cvt8(const float4& v0, const float4& v1,
                                     half8& h, half8& l) {
    float vv[8] = {v0.x, v0.y, v0.z, v0.w, v1.x, v1.y, v1.z, v1.w};
    #pragma unroll
    for (int j = 0; j < 8; ++j) {
        _Float16 hh = (_Float16)vv[j];
        h[j] = hh;
        l[j] = (_Float16)(vv[j] - (float)hh);
    }
}

// Convert staged registers to f16 hi/lo and write one LDS buffer.
// Odd lanes write their two A-chunks in reversed order: per-instr slot set
// becomes {0,3}^(r&3) / {1,2}^(r&3) -> all four 16B slots per bank-half ->
// conflict-free writes (plain order would 2-way conflict).
__device__ __forceinline__ void stage_tile(char* dst,
                                           const float4* av, const float4* bv,
                                           int arow, int acol, int brow, int bcol,
                                           int tid) {
    #pragma unroll
    for (int o = 0; o < 2; ++o) {
        int oo = (tid & 1) ? (1 - o) : o;
        half8 h, l; cvt8(av[2 * oo], av[2 * oo + 1], h, l);
        int cb = acol * 2 + oo * 16;
        *(half8*)(dst + AH_OFF + swz(arow, cb)) = h;
        *(half8*)(dst + AL_OFF + swz(arow, cb)) = l;
    }
    half8 h, l; cvt8(bv[0], bv[1], h, l);
    *(half8*)(dst + BH_OFF + swz(brow, bcol * 2)) = h;
    *(half8*)(dst + BL_OFF + swz(brow, bcol * 2)) = l;
}

// K1: energy = Q.K^T per batch via split-f16 MFMA (hi*hi + hi*lo + lo*hi,
// lo*lo dropped: residual ~1e-5 << typical top-2 gap ~5), fused row-argmax
// epilogue -> packed atomicMax.
__global__ __launch_bounds__(256, 2)
void energy_argmax_kernel(const float* __restrict__ q,    // rgb   [B][C][HW]
                          const float* __restrict__ kmat, // depth [B][C][HW]
                          unsigned long long* __restrict__ best) // [B][C]
{
    const int b   = blockIdx.z;
    const int c0  = blockIdx.y * BM;   // 4 row-tiles
    const int d0  = blockIdx.x * BN;   // 8 col-tiles
    const int tid = threadIdx.x;
    const int lane = tid & 63;
    const int w    = tid >> 6;
    const int wm   = w >> 1;           // wave row (0,1): 64 rows each
    const int wn   = w & 1;            // wave col (0,1): 32 cols each

    __shared__ __align__(16) char sm[2 * BUF_SZ];

    const float* qb = q    + (size_t)b * CH * HW;
    const float* kb = kmat + (size_t)b * CH * HW;

    // staging assignment: A: 2 thr/row, 16 f32 each ; B: 4 thr/row, 8 f32 each
    const int arow = tid >> 1, acol = (tid & 1) * 16;   // f32 units
    const int brow = tid >> 2, bcol = (tid & 3) * 8;
    const float* aG = qb + (size_t)(c0 + arow) * HW + acol;
    const float* bG = kb + (size_t)(d0 + brow) * HW + bcol;

    float4 av[4], bv[2];

    // ---- prologue: stage tile 0 into buf0 ----
    #pragma unroll
    for (int i = 0; i < 4; ++i) av[i] = *(const float4*)(aG + i * 4);
    #pragma unroll
    for (int i = 0; i < 2; ++i) bv[i] = *(const float4*)(bG + i * 4);
    stage_tile(sm, av, bv, arow, acol, brow, bcol, tid);
    __syncthreads();

    f32x16 acc0 = {}, acc1 = {};

    const int rA0 = wm * 64 + (lane & 31);      // A rows for frag mi=0 (+32 for mi=1)
    const int rB  = wn * 32 + (lane & 31);      // B row (= energy col d, local)
    const int hb  = (lane >> 5) * 16;           // 16B half-select within K16

    for (int kt = 0; kt < NKT; ++kt) {
        const char* buf = sm + (size_t)(kt & 1) * BUF_SZ;
        // issue next tile's global loads early; latency hides under MFMA phase
        if (kt + 1 < NKT) {
            const float* ap = aG + (kt + 1) * BK;
            const float* bp = bG + (kt + 1) * BK;
            #pragma unroll
            for (int i = 0; i < 4; ++i) av[i] = *(const float4*)(ap + i * 4);
            #pragma unroll
            for (int i = 0; i < 2; ++i) bv[i] = *(const float4*)(bp + i * 4);
        }
        #pragma unroll
        for (int kc = 0; kc < 2; ++kc) {
            const int cb = kc * 32 + hb;
            half8 ah0 = *(const half8*)(buf + AH_OFF + swz(rA0,      cb));
            half8 ah1 = *(const half8*)(buf + AH_OFF + swz(rA0 + 32, cb));
            half8 al0 = *(const half8*)(buf + AL_OFF + swz(rA0,      cb));
            half8 al1 = *(const half8*)(buf + AL_OFF + swz(rA0 + 32, cb));
            half8 bh  = *(const half8*)(buf + BH_OFF + swz(rB, cb));
            half8 bl  = *(const half8*)(buf + BL_OFF + swz(rB, cb));
            acc0 = __builtin_amdgcn_mfma_f32_32x32x16_f16(ah0, bh, acc0, 0, 0, 0);
            acc1 = __builtin_amdgcn_mfma_f32_32x32x16_f16(ah1, bh, acc1, 0, 0, 0);
            acc0 = __builtin_amdgcn_mfma_f32_32x32x16_f16(ah0, bl, acc0, 0, 0, 0);
            acc1 = __builtin_amdgcn_mfma_f32_32x32x16_f16(ah1, bl, acc1, 0, 0, 0);
            acc0 = __builtin_amdgcn_mfma_f32_32x32x16_f16(al0, bh, acc0, 0, 0, 0);
            acc1 = __builtin_amdgcn_mfma_f32_32x32x16_f16(al1, bh, acc1, 0, 0, 0);
        }
        // convert + write next tile into the other buffer
        if (kt + 1 < NKT) {
            char* dst = sm + (size_t)((kt + 1) & 1) * BUF_SZ;
            stage_tile(dst, av, bv, arow, acol, brow, bcol, tid);
        }
        __syncthreads();
    }

    // ---- epilogue: per-row argmax over this 32-col wave tile ----
    // C/D map (m74/m101): col = lane&31, row = (reg&3) + 8*(reg>>2) + 4*(lane>>5)
    const int dcol = d0 + wn * 32 + (lane & 31);
    const uint32_t didx = ~(uint32_t)dcol;   // ties -> smallest d
    #pragma unroll
    for (int mi = 0; mi < 2; ++mi) {
        #pragma unroll
        for (int qr = 0; qr < 16; ++qr) {
            float v = (mi == 0) ? acc0[qr] : acc1[qr];
            int rowl = wm * 64 + mi * 32 + (qr & 3) + 8 * (qr >> 2) + 4 * (lane >> 5);
            unsigned long long p =
                ((unsigned long long)f32_sortable(v) << 32) | didx;
            #pragma unroll
            for (int off = 1; off < 32; off <<= 1) {   // reduce 32 cols (stays in half)
                unsigned long long o = __shfl_xor(p, off, 64);
                if (o > p) p = o;
            }
            if ((lane & 31) == 0)
                atomicMax(&best[(size_t)b * CH + c0 + rowl], p);
        }
    }
}

// K2: out[b][c][:] = rgb[b][c][:] + depth[b][argmax][:]
__global__ __launch_bounds__(256)
void gather_add_kernel(const float* __restrict__ rgb,
                       const float* __restrict__ depth,
                       const unsigned long long* __restrict__ best,
                       float* __restrict__ out)
{
    const int row = blockIdx.x;          // b*CH + c
    const int b   = row >> 9;            // /512
    const uint32_t idx = ~(uint32_t)(best[row] & 0xFFFFFFFFull);
    const float4* src = (const float4*)(rgb   + (size_t)row * HW);
    const float4* dep = (const float4*)(depth + ((size_t)b * CH + idx) * HW);
    float4*       dst = (float4*)(out + (size_t)row * HW);
    for (int j = threadIdx.x; j < HW / 4; j += 256) {
        float4 a = src[j], d = dep[j];
        float4 r; r.x = a.x + d.x; r.y = a.y + d.y; r.z = a.z + d.z; r.w = a.w + d.w;
        dst[j] = r;
    }
}

extern "C" void kernel_launch(void* const* d_in, const int* in_sizes, int n_in,
                              void* d_out, int out_size, void* d_ws, size_t ws_size,
                              hipStream_t stream)
{
    const float* rgb   = (const float*)d_in[0];
    const float* depth = (const float*)d_in[1];
    float* out = (float*)d_out;
    unsigned long long* best = (unsigned long long*)d_ws;  // 16*512*8 = 64 KB

    hipMemsetAsync(best, 0, (size_t)BATCH * CH * sizeof(unsigned long long), stream);

    dim3 g1(CH / BN, CH / BM, BATCH);   // 8 x 4 x 16 = 512 blocks (2/CU)
    energy_argmax_kernel<<<g1, 256, 0, stream>>>(rgb, depth, best);

    gather_add_kernel<<<BATCH * CH, 256, 0, stream>>>(rgb, depth, best, out);
}

// Round 5
// 156.510 us; speedup vs baseline: 2.1450x; 1.7154x over previous
//
#include <hip/hip_runtime.h>
#include <stdint.h>

// Problem constants (fixed by reference)
#define BATCH 16
#define CH    512
#define HW    2304           // 48*48
#define BM    128
#define BN    64
#define BK    32
#define NKT   (HW / BK)      // 72 K-steps

typedef _Float16 half8  __attribute__((ext_vector_type(8)));
typedef float    f32x16 __attribute__((ext_vector_type(16)));

// LDS byte layout per buffer: A-hi | A-lo | B-hi | B-lo
#define AH_OFF 0
#define AL_OFF 8192          // 128 rows * 64B
#define BH_OFF 16384
#define BL_OFF 20480         // 64 rows * 64B
#define BUF_SZ 24576         // 24 KB ; x2 buffers = 48 KB

// float -> order-preserving uint32
__device__ __forceinline__ uint32_t f32_sortable(float f) {
    uint32_t u = __float_as_uint(f);
    return (u & 0x80000000u) ? ~u : (u | 0x80000000u);
}

// Swizzled byte offset in a [rows][32 f16] tile (row pitch 64B).
// Slot (16B unit, bits 4-5) XORed with (r&3): stays inside the row -> bijective.
// Wave b128 reads (rows = lane&31, fixed slot): 8 words/bank = conflict-free
// floor. A-writes are 4-way conflicted (~1.58x on 1/3 of LDS instrs) -- DO NOT
// "fix" with runtime-reversed write order: R4 did, the runtime index sent the
// prefetch registers to scratch (rule #20) and cost ~200us of HBM traffic.
__device__ __forceinline__ int swz(int r, int cb) {
    return r * 64 + (cb ^ ((r & 3) << 4));
}

__device__ __forceinline__ void cvt8(const float4& v0, const float4& v1,
                                     half8& h, half8& l) {
    float vv[8] = {v0.x, v0.y, v0.z, v0.w, v1.x, v1.y, v1.z, v1.w};
    #pragma unroll
    for (int j = 0; j < 8; ++j) {
        _Float16 hh = (_Float16)vv[j];
        h[j] = hh;
        l[j] = (_Float16)(vv[j] - (float)hh);
    }
}

// Convert staged registers to f16 hi/lo and write one LDS buffer.
// ALL indices compile-time constant so av/bv stay in VGPRs.
__device__ __forceinline__ void stage_tile(char* dst,
                                           const float4 av[4], const float4 bv[2],
                                           int arow, int acol, int brow, int bcol) {
    half8 h, l;
    cvt8(av[0], av[1], h, l);
    *(half8*)(dst + AH_OFF + swz(arow, acol * 2)) = h;
    *(half8*)(dst + AL_OFF + swz(arow, acol * 2)) = l;
    cvt8(av[2], av[3], h, l);
    *(half8*)(dst + AH_OFF + swz(arow, acol * 2 + 16)) = h;
    *(half8*)(dst + AL_OFF + swz(arow, acol * 2 + 16)) = l;
    cvt8(bv[0], bv[1], h, l);
    *(half8*)(dst + BH_OFF + swz(brow, bcol * 2)) = h;
    *(half8*)(dst + BL_OFF + swz(brow, bcol * 2)) = l;
}

// K1: energy = Q.K^T per batch via split-f16 MFMA (hi*hi + hi*lo + lo*hi,
// lo*lo dropped: residual ~1e-5 << typical top-2 gap ~5), fused row-argmax
// epilogue -> packed atomicMax.
__global__ __launch_bounds__(256, 2)
void energy_argmax_kernel(const float* __restrict__ q,    // rgb   [B][C][HW]
                          const float* __restrict__ kmat, // depth [B][C][HW]
                          unsigned long long* __restrict__ best) // [B][C]
{
    const int b   = blockIdx.z;
    const int c0  = blockIdx.y * BM;   // 4 row-tiles
    const int d0  = blockIdx.x * BN;   // 8 col-tiles
    const int tid = threadIdx.x;
    const int lane = tid & 63;
    const int w    = tid >> 6;
    const int wm   = w >> 1;           // wave row (0,1): 64 rows each
    const int wn   = w & 1;            // wave col (0,1): 32 cols each

    __shared__ __align__(16) char sm[2 * BUF_SZ];

    const float* qb = q    + (size_t)b * CH * HW;
    const float* kb = kmat + (size_t)b * CH * HW;

    // staging assignment: A: 2 thr/row, 16 f32 each ; B: 4 thr/row, 8 f32 each
    const int arow = tid >> 1, acol = (tid & 1) * 16;   // f32 units
    const int brow = tid >> 2, bcol = (tid & 3) * 8;
    const float* aG = qb + (size_t)(c0 + arow) * HW + acol;
    const float* bG = kb + (size_t)(d0 + brow) * HW + bcol;

    float4 av[4], bv[2];

    // ---- prologue: stage tile 0 into buf0 ----
    #pragma unroll
    for (int i = 0; i < 4; ++i) av[i] = *(const float4*)(aG + i * 4);
    #pragma unroll
    for (int i = 0; i < 2; ++i) bv[i] = *(const float4*)(bG + i * 4);
    stage_tile(sm, av, bv, arow, acol, brow, bcol);
    __syncthreads();

    f32x16 acc0 = {}, acc1 = {};

    const int rA0 = wm * 64 + (lane & 31);      // A rows for frag mi=0 (+32 for mi=1)
    const int rB  = wn * 32 + (lane & 31);      // B row (= energy col d, local)
    const int hb  = (lane >> 5) * 16;           // 16B half-select within K16

    for (int kt = 0; kt < NKT; ++kt) {
        const char* buf = sm + (size_t)(kt & 1) * BUF_SZ;
        // issue next tile's global loads early; latency hides under MFMA phase
        if (kt + 1 < NKT) {
            const float* ap = aG + (kt + 1) * BK;
            const float* bp = bG + (kt + 1) * BK;
            #pragma unroll
            for (int i = 0; i < 4; ++i) av[i] = *(const float4*)(ap + i * 4);
            #pragma unroll
            for (int i = 0; i < 2; ++i) bv[i] = *(const float4*)(bp + i * 4);
        }
        #pragma unroll
        for (int kc = 0; kc < 2; ++kc) {
            const int cb = kc * 32 + hb;
            half8 ah0 = *(const half8*)(buf + AH_OFF + swz(rA0,      cb));
            half8 ah1 = *(const half8*)(buf + AH_OFF + swz(rA0 + 32, cb));
            half8 al0 = *(const half8*)(buf + AL_OFF + swz(rA0,      cb));
            half8 al1 = *(const half8*)(buf + AL_OFF + swz(rA0 + 32, cb));
            half8 bh  = *(const half8*)(buf + BH_OFF + swz(rB, cb));
            half8 bl  = *(const half8*)(buf + BL_OFF + swz(rB, cb));
            acc0 = __builtin_amdgcn_mfma_f32_32x32x16_f16(ah0, bh, acc0, 0, 0, 0);
            acc1 = __builtin_amdgcn_mfma_f32_32x32x16_f16(ah1, bh, acc1, 0, 0, 0);
            acc0 = __builtin_amdgcn_mfma_f32_32x32x16_f16(ah0, bl, acc0, 0, 0, 0);
            acc1 = __builtin_amdgcn_mfma_f32_32x32x16_f16(ah1, bl, acc1, 0, 0, 0);
            acc0 = __builtin_amdgcn_mfma_f32_32x32x16_f16(al0, bh, acc0, 0, 0, 0);
            acc1 = __builtin_amdgcn_mfma_f32_32x32x16_f16(al1, bh, acc1, 0, 0, 0);
        }
        // convert + write next tile into the other buffer
        if (kt + 1 < NKT) {
            char* dst = sm + (size_t)((kt + 1) & 1) * BUF_SZ;
            stage_tile(dst, av, bv, arow, acol, brow, bcol);
        }
        __syncthreads();
    }

    // ---- epilogue: per-row argmax over this 32-col wave tile ----
    // C/D map (m74/m101): col = lane&31, row = (reg&3) + 8*(reg>>2) + 4*(lane>>5)
    const int dcol = d0 + wn * 32 + (lane & 31);
    const uint32_t didx = ~(uint32_t)dcol;   // ties -> smallest d
    #pragma unroll
    for (int mi = 0; mi < 2; ++mi) {
        #pragma unroll
        for (int qr = 0; qr < 16; ++qr) {
            float v = (mi == 0) ? acc0[qr] : acc1[qr];
            int rowl = wm * 64 + mi * 32 + (qr & 3) + 8 * (qr >> 2) + 4 * (lane >> 5);
            unsigned long long p =
                ((unsigned long long)f32_sortable(v) << 32) | didx;
            #pragma unroll
            for (int off = 1; off < 32; off <<= 1) {   // reduce 32 cols (stays in half)
                unsigned long long o = __shfl_xor(p, off, 64);
                if (o > p) p = o;
            }
            if ((lane & 31) == 0)
                atomicMax(&best[(size_t)b * CH + c0 + rowl], p);
        }
    }
}

// K2: out[b][c][:] = rgb[b][c][:] + depth[b][argmax][:]
__global__ __launch_bounds__(256)
void gather_add_kernel(const float* __restrict__ rgb,
                       const float* __restrict__ depth,
                       const unsigned long long* __restrict__ best,
                       float* __restrict__ out)
{
    const int row = blockIdx.x;          // b*CH + c
    const int b   = row >> 9;            // /512
    const uint32_t idx = ~(uint32_t)(best[row] & 0xFFFFFFFFull);
    const float4* src = (const float4*)(rgb   + (size_t)row * HW);
    const float4* dep = (const float4*)(depth + ((size_t)b * CH + idx) * HW);
    float4*       dst = (float4*)(out + (size_t)row * HW);
    for (int j = threadIdx.x; j < HW / 4; j += 256) {
        float4 a = src[j], d = dep[j];
        float4 r; r.x = a.x + d.x; r.y = a.y + d.y; r.z = a.z + d.z; r.w = a.w + d.w;
        dst[j] = r;
    }
}

extern "C" void kernel_launch(void* const* d_in, const int* in_sizes, int n_in,
                              void* d_out, int out_size, void* d_ws, size_t ws_size,
                              hipStream_t stream)
{
    const float* rgb   = (const float*)d_in[0];
    const float* depth = (const float*)d_in[1];
    float* out = (float*)d_out;
    unsigned long long* best = (unsigned long long*)d_ws;  // 16*512*8 = 64 KB

    hipMemsetAsync(best, 0, (size_t)BATCH * CH * sizeof(unsigned long long), stream);

    dim3 g1(CH / BN, CH / BM, BATCH);   // 8 x 4 x 16 = 512 blocks (2/CU)
    energy_argmax_kernel<<<g1, 256, 0, stream>>>(rgb, depth, best);

    gather_add_kernel<<<BATCH * CH, 256, 0, stream>>>(rgb, depth, best, out);
}

// Round 6
// 147.285 us; speedup vs baseline: 2.2793x; 1.0626x over previous
//
#include <hip/hip_runtime.h>
#include <stdint.h>

// Problem constants (fixed by reference)
#define BATCH 16
#define CH    512
#define HW    2304           // 48*48
#define BM    128
#define BN    64
#define BK    32
#define NKT   (HW / BK)      // 72 K-steps

typedef _Float16 half8  __attribute__((ext_vector_type(8)));
typedef float    f32x16 __attribute__((ext_vector_type(16)));

// LDS byte layout per buffer: A-hi | A-lo | B-hi | B-lo
#define AH_OFF 0
#define AL_OFF 8192          // 128 rows * 64B
#define BH_OFF 16384
#define BL_OFF 20480         // 64 rows * 64B
#define BUF_SZ 24576         // 24 KB ; x2 buffers = 48 KB

// float -> order-preserving uint32
__device__ __forceinline__ uint32_t f32_sortable(float f) {
    uint32_t u = __float_as_uint(f);
    return (u & 0x80000000u) ? ~u : (u | 0x80000000u);
}

// Swizzled byte offset in a [rows][32 f16] tile (row pitch 64B, 4 x 16B slots).
// slot ^= (r&3). b128 bank-group = 16*(r&1) + 4*slot: an instr is conflict-free
// at the 8-round floor iff its lanes spread evenly over the 8 (r&1,slot-pair)
// groups. Reads (slot-set {s,s^1} per instr) are balanced; A-writes must ALSO
// present bit0-paired slot-sets -> each thread owns slots {half, 2+half}
// (R5 had {2*half+o} = bit1-pairs -> rows r,r+2 collided -> 26M conflict cyc).
__device__ __forceinline__ int swz(int r, int cb) {
    return r * 64 + (cb ^ ((r & 3) << 4));
}

__device__ __forceinline__ void cvt8(const float4& v0, const float4& v1,
                                     half8& h, half8& l) {
    float vv[8] = {v0.x, v0.y, v0.z, v0.w, v1.x, v1.y, v1.z, v1.w};
    #pragma unroll
    for (int j = 0; j < 8; ++j) {
        _Float16 hh = (_Float16)vv[j];
        h[j] = hh;
        l[j] = (_Float16)(vv[j] - (float)hh);
    }
}

// Issue global loads for one K-tile into a named register set (static indices).
// A: thread t covers row tid>>1, f32 slots {half, 2+half} (half = t&1):
//    av[j] <- [ (j>>1)*16 + half*8 + (j&1)*4 ]
__device__ __forceinline__ void load_tile(const float* aG, const float* bG, int k0,
                                          float4 (&av)[4], float4 (&bv)[2], int half) {
    av[0] = *(const float4*)(aG + k0 + half * 8 + 0);
    av[1] = *(const float4*)(aG + k0 + half * 8 + 4);
    av[2] = *(const float4*)(aG + k0 + half * 8 + 16);
    av[3] = *(const float4*)(aG + k0 + half * 8 + 20);
    bv[0] = *(const float4*)(bG + k0 + 0);
    bv[1] = *(const float4*)(bG + k0 + 4);
}

// Convert registers to f16 hi/lo and write one LDS buffer. Static indices only.
// A write o: slot 2o+half -> per-instr slot-set {2o, 2o+1} -> bank-balanced.
__device__ __forceinline__ void stage_tile(char* dst,
                                           const float4 (&av)[4], const float4 (&bv)[2],
                                           int arow, int half, int brow, int bq) {
    half8 h, l;
    cvt8(av[0], av[1], h, l);                       // f32 [8h : 8h+8] -> slot half
    *(half8*)(dst + AH_OFF + swz(arow, half * 16)) = h;
    *(half8*)(dst + AL_OFF + swz(arow, half * 16)) = l;
    cvt8(av[2], av[3], h, l);                       // f32 [16+8h : 24+8h] -> slot 2+half
    *(half8*)(dst + AH_OFF + swz(arow, 32 + half * 16)) = h;
    *(half8*)(dst + AL_OFF + swz(arow, 32 + half * 16)) = l;
    cvt8(bv[0], bv[1], h, l);
    *(half8*)(dst + BH_OFF + swz(brow, bq * 16)) = h;
    *(half8*)(dst + BL_OFF + swz(brow, bq * 16)) = l;
}

// One K32 step of MFMA work from one LDS buffer.
__device__ __forceinline__ void compute_tile(const char* buf, int rA0, int rB, int hb,
                                             f32x16& acc0, f32x16& acc1) {
    #pragma unroll
    for (int kc = 0; kc < 2; ++kc) {
        const int cb = kc * 32 + hb;
        half8 ah0 = *(const half8*)(buf + AH_OFF + swz(rA0,      cb));
        half8 ah1 = *(const half8*)(buf + AH_OFF + swz(rA0 + 32, cb));
        half8 al0 = *(const half8*)(buf + AL_OFF + swz(rA0,      cb));
        half8 al1 = *(const half8*)(buf + AL_OFF + swz(rA0 + 32, cb));
        half8 bh  = *(const half8*)(buf + BH_OFF + swz(rB, cb));
        half8 bl  = *(const half8*)(buf + BL_OFF + swz(rB, cb));
        acc0 = __builtin_amdgcn_mfma_f32_32x32x16_f16(ah0, bh, acc0, 0, 0, 0);
        acc1 = __builtin_amdgcn_mfma_f32_32x32x16_f16(ah1, bh, acc1, 0, 0, 0);
        acc0 = __builtin_amdgcn_mfma_f32_32x32x16_f16(ah0, bl, acc0, 0, 0, 0);
        acc1 = __builtin_amdgcn_mfma_f32_32x32x16_f16(ah1, bl, acc1, 0, 0, 0);
        acc0 = __builtin_amdgcn_mfma_f32_32x32x16_f16(al0, bh, acc0, 0, 0, 0);
        acc1 = __builtin_amdgcn_mfma_f32_32x32x16_f16(al1, bh, acc1, 0, 0, 0);
    }
}

// K1: energy = Q.K^T per batch via split-f16 MFMA (hi*hi + hi*lo + lo*hi,
// lo*lo dropped: residual ~1e-5 << typical top-2 gap ~5), fused row-argmax
// epilogue -> packed atomicMax. Depth-2 pipeline: loads for tile t+2 issued
// a full phase before their stage -> vmcnt wait ~0 exposed.
__global__ __launch_bounds__(256, 2)
void energy_argmax_kernel(const float* __restrict__ q,    // rgb   [B][C][HW]
                          const float* __restrict__ kmat, // depth [B][C][HW]
                          unsigned long long* __restrict__ best) // [B][C]
{
    const int b   = blockIdx.z;
    const int c0  = blockIdx.y * BM;   // 4 row-tiles
    const int d0  = blockIdx.x * BN;   // 8 col-tiles
    const int tid = threadIdx.x;
    const int lane = tid & 63;
    const int w    = tid >> 6;
    const int wm   = w >> 1;           // wave row (0,1): 64 rows each
    const int wn   = w & 1;            // wave col (0,1): 32 cols each

    __shared__ __align__(16) char sm[2 * BUF_SZ];
    char* buf0 = sm;
    char* buf1 = sm + BUF_SZ;

    const float* qb = q    + (size_t)b * CH * HW;
    const float* kb = kmat + (size_t)b * CH * HW;

    // staging assignment: A: 2 thr/row ; B: 4 thr/row (one 16B slot each)
    const int arow = tid >> 1, half = tid & 1;
    const int brow = tid >> 2, bq   = tid & 3;
    const float* aG = qb + (size_t)(c0 + arow) * HW;
    const float* bG = kb + (size_t)(d0 + brow) * HW + bq * 8;

    float4 av0[4], bv0[2], av1[4], bv1[2];

    // ---- prologue: tile0 -> buf0 ; tile1 loads in flight ----
    load_tile(aG, bG, 0, av0, bv0, half);
    stage_tile(buf0, av0, bv0, arow, half, brow, bq);
    load_tile(aG, bG, BK, av1, bv1, half);
    __syncthreads();

    f32x16 acc0 = {}, acc1 = {};

    const int rA0 = wm * 64 + (lane & 31);      // A rows for frag mi=0 (+32 for mi=1)
    const int rB  = wn * 32 + (lane & 31);      // B row (= energy col d, local)
    const int hb  = (lane >> 5) * 16;           // 16B half-select within K16

    for (int kt = 0; kt < NKT; kt += 2) {
        // phase A: compute tile kt (buf0); stage tile kt+1 -> buf1
        if (kt + 2 < NKT) load_tile(aG, bG, (kt + 2) * BK, av0, bv0, half);
        compute_tile(buf0, rA0, rB, hb, acc0, acc1);
        stage_tile(buf1, av1, bv1, arow, half, brow, bq);
        __syncthreads();
        // phase B: compute tile kt+1 (buf1); stage tile kt+2 -> buf0
        if (kt + 3 < NKT) load_tile(aG, bG, (kt + 3) * BK, av1, bv1, half);
        compute_tile(buf1, rA0, rB, hb, acc0, acc1);
        if (kt + 2 < NKT) stage_tile(buf0, av0, bv0, arow, half, brow, bq);
        __syncthreads();
    }

    // ---- epilogue: per-row argmax over this 32-col wave tile ----
    // C/D map (m74/m101): col = lane&31, row = (reg&3) + 8*(reg>>2) + 4*(lane>>5)
    const int dcol = d0 + wn * 32 + (lane & 31);
    const uint32_t didx = ~(uint32_t)dcol;   // ties -> smallest d
    #pragma unroll
    for (int mi = 0; mi < 2; ++mi) {
        #pragma unroll
        for (int qr = 0; qr < 16; ++qr) {
            float v = (mi == 0) ? acc0[qr] : acc1[qr];
            int rowl = wm * 64 + mi * 32 + (qr & 3) + 8 * (qr >> 2) + 4 * (lane >> 5);
            unsigned long long p =
                ((unsigned long long)f32_sortable(v) << 32) | didx;
            #pragma unroll
            for (int off = 1; off < 32; off <<= 1) {   // reduce 32 cols (stays in half)
                unsigned long long o = __shfl_xor(p, off, 64);
                if (o > p) p = o;
            }
            if ((lane & 31) == 0)
                atomicMax(&best[(size_t)b * CH + c0 + rowl], p);
        }
    }
}

// K2: out[b][c][:] = rgb[b][c][:] + depth[b][argmax][:]
__global__ __launch_bounds__(256)
void gather_add_kernel(const float* __restrict__ rgb,
                       const float* __restrict__ depth,
                       const unsigned long long* __restrict__ best,
                       float* __restrict__ out)
{
    const int row = blockIdx.x;          // b*CH + c
    const int b   = row >> 9;            // /512
    const uint32_t idx = ~(uint32_t)(best[row] & 0xFFFFFFFFull);
    const float4* src = (const float4*)(rgb   + (size_t)row * HW);
    const float4* dep = (const float4*)(depth + ((size_t)b * CH + idx) * HW);
    float4*       dst = (float4*)(out + (size_t)row * HW);
    for (int j = threadIdx.x; j < HW / 4; j += 256) {
        float4 a = src[j], d = dep[j];
        float4 r; r.x = a.x + d.x; r.y = a.y + d.y; r.z = a.z + d.z; r.w = a.w + d.w;
        dst[j] = r;
    }
}

extern "C" void kernel_launch(void* const* d_in, const int* in_sizes, int n_in,
                              void* d_out, int out_size, void* d_ws, size_t ws_size,
                              hipStream_t stream)
{
    const float* rgb   = (const float*)d_in[0];
    const float* depth = (const float*)d_in[1];
    float* out = (float*)d_out;
    unsigned long long* best = (unsigned long long*)d_ws;  // 16*512*8 = 64 KB

    hipMemsetAsync(best, 0, (size_t)BATCH * CH * sizeof(unsigned long long), stream);

    dim3 g1(CH / BN, CH / BM, BATCH);   // 8 x 4 x 16 = 512 blocks (2/CU)
    energy_argmax_kernel<<<g1, 256, 0, stream>>>(rgb, depth, best);

    gather_add_kernel<<<BATCH * CH, 256, 0, stream>>>(rgb, depth, best, out);
}

// Round 7
// 126.857 us; speedup vs baseline: 2.6464x; 1.1610x over previous
//
#include <hip/hip_runtime.h>
#include <stdint.h>

// Problem constants (fixed by reference)
#define BATCH 16
#define CH    512
#define HW    2304           // 48*48
#define BM    128
#define BN    128
#define BK    32
#define NKT   (HW / BK)      // 72 K-steps

typedef _Float16 half8  __attribute__((ext_vector_type(8)));
typedef float    f32x16 __attribute__((ext_vector_type(16)));

// LDS byte layout per buffer: A-hi | A-lo | B-hi | B-lo (each 128 rows x 64B)
#define AH_OFF 0
#define AL_OFF 8192
#define BH_OFF 16384
#define BL_OFF 24576
#define BUF_SZ 32768         // 32 KB ; x2 buffers = 64 KB (1 block/CU)

#define MFMA16 __builtin_amdgcn_mfma_f32_32x32x16_f16

// float -> order-preserving uint32
__device__ __forceinline__ uint32_t f32_sortable(float f) {
    uint32_t u = __float_as_uint(f);
    return (u & 0x80000000u) ? ~u : (u | 0x80000000u);
}

// Swizzled byte offset in a [rows][32 f16] tile (row pitch 64B, 4 x 16B slots).
// slot ^= (r&3); b128 bank-group = (r&1, slot-pair). Reads and writes both
// present bit0-paired slot-sets -> balanced over all 8 groups (R5/R6 derivation).
__device__ __forceinline__ int swz(int r, int cb) {
    return r * 64 + (cb ^ ((r & 3) << 4));
}

__device__ __forceinline__ void cvt8(const float4& v0, const float4& v1,
                                     half8& h, half8& l) {
    float vv[8] = {v0.x, v0.y, v0.z, v0.w, v1.x, v1.y, v1.z, v1.w};
    #pragma unroll
    for (int j = 0; j < 8; ++j) {
        _Float16 hh = (_Float16)vv[j];
        h[j] = hh;
        l[j] = (_Float16)(vv[j] - (float)hh);
    }
}

// Issue global loads for one K-tile (A and B symmetric: 2 thr/row, 16 f32 each,
// thread owns f32 slots {half, 2+half}). Static indices only (rule #20).
__device__ __forceinline__ void load_tile(const float* aG, const float* bG, int k0,
                                          float4 (&av)[4], float4 (&bv)[4], int half) {
    av[0] = *(const float4*)(aG + k0 + half * 8 + 0);
    av[1] = *(const float4*)(aG + k0 + half * 8 + 4);
    av[2] = *(const float4*)(aG + k0 + half * 8 + 16);
    av[3] = *(const float4*)(aG + k0 + half * 8 + 20);
    bv[0] = *(const float4*)(bG + k0 + half * 8 + 0);
    bv[1] = *(const float4*)(bG + k0 + half * 8 + 4);
    bv[2] = *(const float4*)(bG + k0 + half * 8 + 16);
    bv[3] = *(const float4*)(bG + k0 + half * 8 + 20);
}

// Convert to f16 hi/lo and write one LDS buffer. Slot-sets {2o, 2o+1} -> balanced.
__device__ __forceinline__ void stage_tile(char* dst,
                                           const float4 (&av)[4], const float4 (&bv)[4],
                                           int row, int half) {
    half8 h, l;
    cvt8(av[0], av[1], h, l);
    *(half8*)(dst + AH_OFF + swz(row, half * 16)) = h;
    *(half8*)(dst + AL_OFF + swz(row, half * 16)) = l;
    cvt8(av[2], av[3], h, l);
    *(half8*)(dst + AH_OFF + swz(row, 32 + half * 16)) = h;
    *(half8*)(dst + AL_OFF + swz(row, 32 + half * 16)) = l;
    cvt8(bv[0], bv[1], h, l);
    *(half8*)(dst + BH_OFF + swz(row, half * 16)) = h;
    *(half8*)(dst + BL_OFF + swz(row, half * 16)) = l;
    cvt8(bv[2], bv[3], h, l);
    *(half8*)(dst + BH_OFF + swz(row, 32 + half * 16)) = h;
    *(half8*)(dst + BL_OFF + swz(row, 32 + half * 16)) = l;
}

// One K32 step: 16 ds_read_b128 -> 24 MFMA (ratio 1.5; R6 was 1.0).
__device__ __forceinline__ void compute_tile(const char* buf, int rA0, int rB0, int hb,
                                             f32x16& a00, f32x16& a01,
                                             f32x16& a10, f32x16& a11) {
    #pragma unroll
    for (int kc = 0; kc < 2; ++kc) {
        const int cb = kc * 32 + hb;
        half8 ah0 = *(const half8*)(buf + AH_OFF + swz(rA0,      cb));
        half8 ah1 = *(const half8*)(buf + AH_OFF + swz(rA0 + 32, cb));
        half8 al0 = *(const half8*)(buf + AL_OFF + swz(rA0,      cb));
        half8 al1 = *(const half8*)(buf + AL_OFF + swz(rA0 + 32, cb));
        half8 bh0 = *(const half8*)(buf + BH_OFF + swz(rB0,      cb));
        half8 bh1 = *(const half8*)(buf + BH_OFF + swz(rB0 + 32, cb));
        half8 bl0 = *(const half8*)(buf + BL_OFF + swz(rB0,      cb));
        half8 bl1 = *(const half8*)(buf + BL_OFF + swz(rB0 + 32, cb));
        a00 = MFMA16(ah0, bh0, a00, 0, 0, 0);
        a01 = MFMA16(ah0, bh1, a01, 0, 0, 0);
        a10 = MFMA16(ah1, bh0, a10, 0, 0, 0);
        a11 = MFMA16(ah1, bh1, a11, 0, 0, 0);
        a00 = MFMA16(ah0, bl0, a00, 0, 0, 0);
        a01 = MFMA16(ah0, bl1, a01, 0, 0, 0);
        a10 = MFMA16(ah1, bl0, a10, 0, 0, 0);
        a11 = MFMA16(ah1, bl1, a11, 0, 0, 0);
        a00 = MFMA16(al0, bh0, a00, 0, 0, 0);
        a01 = MFMA16(al0, bh1, a01, 0, 0, 0);
        a10 = MFMA16(al1, bh0, a10, 0, 0, 0);
        a11 = MFMA16(al1, bh1, a11, 0, 0, 0);
    }
}

// K1: energy = Q.K^T per batch via split-f16 MFMA (hi*hi + hi*lo + lo*hi),
// fused row-argmax -> packed atomicMax. 128x128 block tile, 4 waves of 64x64.
// 256 blocks = 1/CU; XCD-chunked swizzle (256%8==0 -> bijective).
__global__ __launch_bounds__(256, 1)
void energy_argmax_kernel(const float* __restrict__ q,    // rgb   [B][C][HW]
                          const float* __restrict__ kmat, // depth [B][C][HW]
                          unsigned long long* __restrict__ best) // [B][C]
{
    const int bid = blockIdx.x;
    const int nid = (bid & 7) * 32 + (bid >> 3);   // XCD-chunk: each XCD gets 2 batches
    const int d0  = (nid & 3) * BN;
    const int c0  = ((nid >> 2) & 3) * BM;
    const int b   = nid >> 4;

    const int tid = threadIdx.x;
    const int lane = tid & 63;
    const int w    = tid >> 6;
    const int wm   = w >> 1;           // wave row (0,1): 64 rows each
    const int wn   = w & 1;            // wave col (0,1): 64 cols each

    __shared__ __align__(16) char sm[2 * BUF_SZ];
    char* buf0 = sm;
    char* buf1 = sm + BUF_SZ;

    const float* qb = q    + (size_t)b * CH * HW;
    const float* kb = kmat + (size_t)b * CH * HW;

    const int row  = tid >> 1, half = tid & 1;     // staging: 2 thr/row for A and B
    const float* aG = qb + (size_t)(c0 + row) * HW;
    const float* bG = kb + (size_t)(d0 + row) * HW;

    float4 av0[4], bv0[4], av1[4], bv1[4];

    // ---- prologue: tile0 -> buf0 ; tile1 loads in flight ----
    load_tile(aG, bG, 0, av0, bv0, half);
    stage_tile(buf0, av0, bv0, row, half);
    load_tile(aG, bG, BK, av1, bv1, half);
    __syncthreads();

    f32x16 a00 = {}, a01 = {}, a10 = {}, a11 = {};

    const int rA0 = wm * 64 + (lane & 31);
    const int rB0 = wn * 64 + (lane & 31);
    const int hb  = (lane >> 5) * 16;             // 16B half-select within K16

    for (int kt = 0; kt < NKT; kt += 2) {
        if (kt + 2 < NKT) load_tile(aG, bG, (kt + 2) * BK, av0, bv0, half);
        compute_tile(buf0, rA0, rB0, hb, a00, a01, a10, a11);
        stage_tile(buf1, av1, bv1, row, half);
        __syncthreads();
        if (kt + 3 < NKT) load_tile(aG, bG, (kt + 3) * BK, av1, bv1, half);
        compute_tile(buf1, rA0, rB0, hb, a00, a01, a10, a11);
        if (kt + 2 < NKT) stage_tile(buf0, av0, bv0, row, half);
        __syncthreads();
    }

    // ---- epilogue: per-row argmax over this 64-col wave tile ----
    // C/D map (m74/m101): col = lane&31, row = (reg&3) + 8*(reg>>2) + 4*(lane>>5)
    const uint32_t didx0 = ~(uint32_t)(d0 + wn * 64 +      (lane & 31));
    const uint32_t didx1 = ~(uint32_t)(d0 + wn * 64 + 32 + (lane & 31));
    #pragma unroll
    for (int mi = 0; mi < 2; ++mi) {
        #pragma unroll
        for (int qr = 0; qr < 16; ++qr) {
            float v0 = (mi == 0) ? a00[qr] : a10[qr];
            float v1 = (mi == 0) ? a01[qr] : a11[qr];
            int rowl = wm * 64 + mi * 32 + (qr & 3) + 8 * (qr >> 2) + 4 * (lane >> 5);
            unsigned long long p0 =
                ((unsigned long long)f32_sortable(v0) << 32) | didx0;
            unsigned long long p1 =
                ((unsigned long long)f32_sortable(v1) << 32) | didx1;
            unsigned long long p = p0 > p1 ? p0 : p1;
            #pragma unroll
            for (int off = 1; off < 32; off <<= 1) {   // reduce 32 cols (stays in half)
                unsigned long long o = __shfl_xor(p, off, 64);
                if (o > p) p = o;
            }
            if ((lane & 31) == 0)
                atomicMax(&best[(size_t)b * CH + c0 + rowl], p);
        }
    }
}

// K2: out[b][c][:] = rgb[b][c][:] + depth[b][argmax][:]
__global__ __launch_bounds__(256)
void gather_add_kernel(const float* __restrict__ rgb,
                       const float* __restrict__ depth,
                       const unsigned long long* __restrict__ best,
                       float* __restrict__ out)
{
    const int row = blockIdx.x;          // b*CH + c
    const int b   = row >> 9;            // /512
    const uint32_t idx = ~(uint32_t)(best[row] & 0xFFFFFFFFull);
    const float4* src = (const float4*)(rgb   + (size_t)row * HW);
    const float4* dep = (const float4*)(depth + ((size_t)b * CH + idx) * HW);
    float4*       dst = (float4*)(out + (size_t)row * HW);
    for (int j = threadIdx.x; j < HW / 4; j += 256) {
        float4 a = src[j], d = dep[j];
        float4 r; r.x = a.x + d.x; r.y = a.y + d.y; r.z = a.z + d.z; r.w = a.w + d.w;
        dst[j] = r;
    }
}

extern "C" void kernel_launch(void* const* d_in, const int* in_sizes, int n_in,
                              void* d_out, int out_size, void* d_ws, size_t ws_size,
                              hipStream_t stream)
{
    const float* rgb   = (const float*)d_in[0];
    const float* depth = (const float*)d_in[1];
    float* out = (float*)d_out;
    unsigned long long* best = (unsigned long long*)d_ws;  // 16*512*8 = 64 KB

    hipMemsetAsync(best, 0, (size_t)BATCH * CH * sizeof(unsigned long long), stream);

    energy_argmax_kernel<<<256, 256, 0, stream>>>(rgb, depth, best);

    gather_add_kernel<<<BATCH * CH, 256, 0, stream>>>(rgb, depth, best, out);
}

// Round 8
// 119.272 us; speedup vs baseline: 2.8146x; 1.0636x over previous
//
#include <hip/hip_runtime.h>
#include <stdint.h>

// Problem constants (fixed by reference)
#define BATCH 16
#define CH    512
#define HW    2304           // 48*48
#define BM    128
#define BN    128
#define BK    32
#define NKT   (HW / BK)      // 72 K-steps

typedef _Float16 half8  __attribute__((ext_vector_type(8)));
typedef float    f32x16 __attribute__((ext_vector_type(16)));

// LDS byte layout per buffer: A-hi | A-lo | B-hi | B-lo (each 128 rows x 64B)
#define AH_OFF 0
#define AL_OFF 8192
#define BH_OFF 16384
#define BL_OFF 24576
#define BUF_SZ 32768         // 32 KB ; x2 buffers = 64 KB

#define MFMA16 __builtin_amdgcn_mfma_f32_32x32x16_f16

// float -> order-preserving uint32
__device__ __forceinline__ uint32_t f32_sortable(float f) {
    uint32_t u = __float_as_uint(f);
    return (u & 0x80000000u) ? ~u : (u | 0x80000000u);
}

// Swizzled byte offset in a [rows][32 f16] tile (row pitch 64B, 4 x 16B slots).
// R7 used slot ^= (r&3): 14M conflict-cyc remained (~2-way tax on every LDS op)
// -> full-wave balance is NOT sufficient; HW processes b128 in 16-lane phases
// and balance is required WITHIN each phase. (r&3) gives even rows of a
// 16-lane group only 2 distinct slots -> 4/bank vs floor 2. slot ^= (r>>1)&3
// covers all 4 slots over the even (and odd) rows of every 16 consecutive
// lanes, for reads AND both write patterns; row-local -> bijective.
__device__ __forceinline__ int swz(int r, int cb) {
    return r * 64 + (cb ^ (((r >> 1) & 3) << 4));
}

__device__ __forceinline__ void cvt8(const float4& v0, const float4& v1,
                                     half8& h, half8& l) {
    float vv[8] = {v0.x, v0.y, v0.z, v0.w, v1.x, v1.y, v1.z, v1.w};
    #pragma unroll
    for (int j = 0; j < 8; ++j) {
        _Float16 hh = (_Float16)vv[j];
        h[j] = hh;
        l[j] = (_Float16)(vv[j] - (float)hh);
    }
}

// 512-thread staging: thread owns row tid>>2, 16B slot q = tid&3 of A and B.
// Static indices only (rule #20).
__device__ __forceinline__ void load_tile(const float* aG, const float* bG, int k0,
                                          float4 (&av)[2], float4 (&bv)[2], int q) {
    av[0] = *(const float4*)(aG + k0 + q * 8 + 0);
    av[1] = *(const float4*)(aG + k0 + q * 8 + 4);
    bv[0] = *(const float4*)(bG + k0 + q * 8 + 0);
    bv[1] = *(const float4*)(bG + k0 + q * 8 + 4);
}

// Convert to f16 hi/lo and write one LDS buffer (4 b128 writes/thread).
// Write instr lanes: rows tid>>2, slot q^((r>>1)&3): balanced per 16-lane phase.
__device__ __forceinline__ void stage_tile(char* dst,
                                           const float4 (&av)[2], const float4 (&bv)[2],
                                           int row, int q) {
    half8 h, l;
    cvt8(av[0], av[1], h, l);
    *(half8*)(dst + AH_OFF + swz(row, q * 16)) = h;
    *(half8*)(dst + AL_OFF + swz(row, q * 16)) = l;
    cvt8(bv[0], bv[1], h, l);
    *(half8*)(dst + BH_OFF + swz(row, q * 16)) = h;
    *(half8*)(dst + BL_OFF + swz(row, q * 16)) = l;
}

// One K32 step for a 64x32 wave tile: 12 ds_read_b128 -> 12 MFMA.
__device__ __forceinline__ void compute_tile(const char* buf, int rA0, int rB, int hb,
                                             f32x16& acc0, f32x16& acc1) {
    #pragma unroll
    for (int kc = 0; kc < 2; ++kc) {
        const int cb = kc * 32 + hb;
        half8 ah0 = *(const half8*)(buf + AH_OFF + swz(rA0,      cb));
        half8 ah1 = *(const half8*)(buf + AH_OFF + swz(rA0 + 32, cb));
        half8 al0 = *(const half8*)(buf + AL_OFF + swz(rA0,      cb));
        half8 al1 = *(const half8*)(buf + AL_OFF + swz(rA0 + 32, cb));
        half8 bh  = *(const half8*)(buf + BH_OFF + swz(rB, cb));
        half8 bl  = *(const half8*)(buf + BL_OFF + swz(rB, cb));
        acc0 = MFMA16(ah0, bh, acc0, 0, 0, 0);
        acc1 = MFMA16(ah1, bh, acc1, 0, 0, 0);
        acc0 = MFMA16(ah0, bl, acc0, 0, 0, 0);
        acc1 = MFMA16(ah1, bl, acc1, 0, 0, 0);
        acc0 = MFMA16(al0, bh, acc0, 0, 0, 0);
        acc1 = MFMA16(al1, bh, acc1, 0, 0, 0);
    }
}

// K1: energy = Q.K^T per batch via split-f16 MFMA (hi*hi + hi*lo + lo*hi),
// fused row-argmax -> packed atomicMax. 128x128 block tile, 8 waves of 64x32,
// 512 threads -> 2 waves/SIMD (R7's 1/SIMD lockstep exposed all LDS latency).
// 256 blocks = 1/CU; XCD-chunked swizzle (256%8==0 -> bijective).
__global__ __launch_bounds__(512, 1)
void energy_argmax_kernel(const float* __restrict__ q,    // rgb   [B][C][HW]
                          const float* __restrict__ kmat, // depth [B][C][HW]
                          unsigned long long* __restrict__ best) // [B][C]
{
    const int bid = blockIdx.x;
    const int nid = (bid & 7) * 32 + (bid >> 3);   // XCD-chunk: each XCD gets 2 batches
    const int d0  = (nid & 3) * BN;
    const int c0  = ((nid >> 2) & 3) * BM;
    const int b   = nid >> 4;

    const int tid = threadIdx.x;
    const int lane = tid & 63;
    const int w    = tid >> 6;         // 0..7
    const int wm   = w >> 2;           // wave row (0,1): 64 rows each
    const int wn   = w & 3;            // wave col (0..3): 32 cols each

    __shared__ __align__(16) char sm[2 * BUF_SZ];
    char* buf0 = sm;
    char* buf1 = sm + BUF_SZ;

    const float* qb = q    + (size_t)b * CH * HW;
    const float* kb = kmat + (size_t)b * CH * HW;

    const int row = tid >> 2, sq = tid & 3;        // staging: 4 thr/row
    const float* aG = qb + (size_t)(c0 + row) * HW;
    const float* bG = kb + (size_t)(d0 + row) * HW;

    float4 av0[2], bv0[2], av1[2], bv1[2];

    // ---- prologue: tile0 -> buf0 ; tile1 loads in flight ----
    load_tile(aG, bG, 0, av0, bv0, sq);
    stage_tile(buf0, av0, bv0, row, sq);
    load_tile(aG, bG, BK, av1, bv1, sq);
    __syncthreads();

    f32x16 acc0 = {}, acc1 = {};

    const int rA0 = wm * 64 + (lane & 31);
    const int rB  = wn * 32 + (lane & 31);
    const int hb  = (lane >> 5) * 16;              // 16B half-select within K16

    for (int kt = 0; kt < NKT; kt += 2) {
        if (kt + 2 < NKT) load_tile(aG, bG, (kt + 2) * BK, av0, bv0, sq);
        compute_tile(buf0, rA0, rB, hb, acc0, acc1);
        stage_tile(buf1, av1, bv1, row, sq);
        __syncthreads();
        if (kt + 3 < NKT) load_tile(aG, bG, (kt + 3) * BK, av1, bv1, sq);
        compute_tile(buf1, rA0, rB, hb, acc0, acc1);
        if (kt + 2 < NKT) stage_tile(buf0, av0, bv0, row, sq);
        __syncthreads();
    }

    // ---- epilogue: per-row argmax over this 32-col wave tile ----
    // C/D map (m74/m101): col = lane&31, row = (reg&3) + 8*(reg>>2) + 4*(lane>>5)
    const uint32_t didx = ~(uint32_t)(d0 + wn * 32 + (lane & 31));  // ties -> smallest d
    #pragma unroll
    for (int mi = 0; mi < 2; ++mi) {
        #pragma unroll
        for (int qr = 0; qr < 16; ++qr) {
            float v = (mi == 0) ? acc0[qr] : acc1[qr];
            int rowl = wm * 64 + mi * 32 + (qr & 3) + 8 * (qr >> 2) + 4 * (lane >> 5);
            unsigned long long p =
                ((unsigned long long)f32_sortable(v) << 32) | didx;
            #pragma unroll
            for (int off = 1; off < 32; off <<= 1) {   // reduce 32 cols (stays in half)
                unsigned long long o = __shfl_xor(p, off, 64);
                if (o > p) p = o;
            }
            if ((lane & 31) == 0)
                atomicMax(&best[(size_t)b * CH + c0 + rowl], p);
        }
    }
}

// K2: out[b][c][:] = rgb[b][c][:] + depth[b][argmax][:]
__global__ __launch_bounds__(256)
void gather_add_kernel(const float* __restrict__ rgb,
                       const float* __restrict__ depth,
                       const unsigned long long* __restrict__ best,
                       float* __restrict__ out)
{
    const int row = blockIdx.x;          // b*CH + c
    const int b   = row >> 9;            // /512
    const uint32_t idx = ~(uint32_t)(best[row] & 0xFFFFFFFFull);
    const float4* src = (const float4*)(rgb   + (size_t)row * HW);
    const float4* dep = (const float4*)(depth + ((size_t)b * CH + idx) * HW);
    float4*       dst = (float4*)(out + (size_t)row * HW);
    for (int j = threadIdx.x; j < HW / 4; j += 256) {
        float4 a = src[j], d = dep[j];
        float4 r; r.x = a.x + d.x; r.y = a.y + d.y; r.z = a.z + d.z; r.w = a.w + d.w;
        dst[j] = r;
    }
}

extern "C" void kernel_launch(void* const* d_in, const int* in_sizes, int n_in,
                              void* d_out, int out_size, void* d_ws, size_t ws_size,
                              hipStream_t stream)
{
    const float* rgb   = (const float*)d_in[0];
    const float* depth = (const float*)d_in[1];
    float* out = (float*)d_out;
    unsigned long long* best = (unsigned long long*)d_ws;  // 16*512*8 = 64 KB

    hipMemsetAsync(best, 0, (size_t)BATCH * CH * sizeof(unsigned long long), stream);

    energy_argmax_kernel<<<256, 512, 0, stream>>>(rgb, depth, best);

    gather_add_kernel<<<BATCH * CH, 256, 0, stream>>>(rgb, depth, best, out);
}